// Round 2
// baseline (281.426 us; speedup 1.0000x reference)
//
#include <hip/hip_runtime.h>
#include <math.h>

namespace {
constexpr int T    = 4096;
constexpr int C    = 64;
constexpr int NCH  = 4;
constexpr int TDAF = 50;
constexpr double LEAK = 0.9;
}

// ============================ Phase 1: proj ================================
// Block: 128 threads = 32 rows x 4 channels. Rows = 4 b's x 8 t's.
// Each block loops over 8 inner chunks -> covers (4 b's) x (64 t's).
// grid = (B/4) * (T/64).  proj layout: [T][B*NCH] f64.
__global__ __launch_bounds__(128, 2)
void lif_proj(const float* __restrict__ x,    // [B,T,C]
              const float* __restrict__ Wsp,  // [NCH,C]
              const float* __restrict__ lat,  // [NCH,NCH]
              double* __restrict__ proj,      // [T][B*NCH]
              int B)
{
  __shared__ float  xl[32 * 76];      // 32 rows, padded stride 76
  __shared__ double wl[NCH * C];      // W_eff [n][c]
  __shared__ double pl[8 * 17];       // [i][c16], pad 17

  const int tid = threadIdx.x;
  const int nb  = B >> 2;
  const int bq  = blockIdx.x % nb;
  const int tq  = blockIdx.x / nb;
  const int b0  = bq << 2;            // 4 b's
  const int t00 = tq << 6;            // 64 t's
  const int stride = B * NCH;         // 1024

  // W_eff = W_spatial^T @ lateral  (f64)
  #pragma unroll
  for (int k = 0; k < 2; ++k) {
    const int idx = tid + 128 * k;    // 0..255
    const int c = idx >> 2, n = idx & 3;
    double s = 0.0;
    #pragma unroll
    for (int m = 0; m < NCH; ++m)
      s += (double)Wsp[m * C + c] * (double)lat[m * NCH + n];
    wl[n * C + c] = s;
  }
  __syncthreads();

  const int n  = tid & 3;
  const int rr = tid >> 2;            // 0..31 (row within chunk)
  const int bb = rr >> 3, ii = rr & 7;

  double w[C];                        // per-thread channel column (VGPRs)
  #pragma unroll
  for (int j = 0; j < C; ++j) w[j] = wl[n * C + j];

  const float4* gx = reinterpret_cast<const float4*>(x);

  for (int ch = 0; ch < 8; ++ch) {
    const int t0 = t00 + (ch << 3);   // 8 t's this chunk
    __syncthreads();                  // xl/pl free for reuse
    // stage 32 rows x 64 floats (coalesced, 1KB/wave-instr)
    #pragma unroll
    for (int k = 0; k < 4; ++k) {
      const int f   = tid + 128 * k;  // 0..511
      const int row = f >> 4, c4 = f & 15;
      const int wb  = row >> 3, wi = row & 7;
      *reinterpret_cast<float4*>(&xl[row * 76 + c4 * 4]) =
          gx[((size_t)(b0 + wb) * T + (t0 + wi)) * 16 + c4];
    }
    __syncthreads();
    // f64 dot: thread (rr, n)
    const float* rowp = &xl[rr * 76];
    double a0 = 0.0, a1 = 0.0;
    #pragma unroll
    for (int q = 0; q < 16; ++q) {
      const float4 v = *reinterpret_cast<const float4*>(&rowp[4 * q]);
      a0 = fma((double)v.x, w[4 * q + 0], a0);
      a1 = fma((double)v.y, w[4 * q + 1], a1);
      a0 = fma((double)v.z, w[4 * q + 2], a0);
      a1 = fma((double)v.w, w[4 * q + 3], a1);
    }
    pl[ii * 17 + bb * 4 + n] = a0 + a1;
    __syncthreads();
    // coalesced flush: 128 f64, 128B segments
    {
      const int i = tid >> 4, c = tid & 15;
      proj[(size_t)(t0 + i) * stride + b0 * 4 + c] = pl[i * 17 + c];
    }
  }
}

// ============================ Phase 2: scan ================================
// 1 wave per block, 1 chain per lane. grid = B*NCH/64 blocks.
// proj [T][B*NCH]: each wave reads 512B contiguous per step.
// 64-step register prefetch (8 groups x 8, all statically indexed).
__global__ __launch_bounds__(64)
void lif_scan(const double* __restrict__ proj,
              const float* __restrict__ tda,   // [B,TDAF]
              const float* __restrict__ Wtda,  // [NCH,TDAF]
              const float* __restrict__ btda,  // [NCH]
              float* __restrict__ out,         // [B,T,NCH]
              int B)
{
  __shared__ float slds[64 * 65];

  const int lane = threadIdx.x;
  const int g    = blockIdx.x * 64 + lane;   // chain = b*4+n
  const int b    = g >> 2, n = g & 3;
  const int b0   = (blockIdx.x * 64) >> 2;   // first b of this wave
  const int stride = B * NCH;                // 1024

  // dynamic threshold (f64, same math as verified fused kernel)
  double z = (double)btda[n];
  #pragma unroll
  for (int j = 0; j < TDAF; ++j)
    z += (double)tda[b * TDAF + j] * (double)Wtda[n * TDAF + j];
  const double th = 1.0 + 0.3 / (1.0 + exp(-z));

  double pb[8][8];
  #pragma unroll
  for (int j2 = 0; j2 < 8; ++j2)
    #pragma unroll
    for (int e = 0; e < 8; ++e)
      pb[j2][e] = proj[(size_t)(j2 * 8 + e) * stride + g];

  double pre = 0.0;
  bool sflag = true;                 // mem0 = 0  =>  pre_0 = p_0

  for (int t0 = 0; t0 < T; t0 += 64) {
    #pragma unroll
    for (int j2 = 0; j2 < 8; ++j2) {
      #pragma unroll
      for (int e = 0; e < 8; ++e) {
        const double p  = pb[j2][e];
        const double ac = fma(LEAK, pre, p);
        pre   = sflag ? p : ac;
        sflag = (pre >= th);
        slds[(j2 * 8 + e) * 65 + lane] = sflag ? 1.0f : 0.0f;
      }
      // reload this group for t0+64 (uniform clamp keeps loads in-bounds)
      int tt = t0 + 64 + j2 * 8;
      tt = (tt < T) ? tt : (T - 64);
      #pragma unroll
      for (int e = 0; e < 8; ++e)
        pb[j2][e] = proj[(size_t)(tt + e) * stride + g];
    }
    __syncthreads();
    // coalesced spike flush: 16 b's x 256 elems (256B per wave-instr)
    #pragma unroll
    for (int bb = 0; bb < 16; ++bb) {
      #pragma unroll
      for (int h = 0; h < 4; ++h) {
        const int flat = lane + 64 * h;        // 0..255
        const int i = flat >> 2, nn = flat & 3;
        out[((size_t)(b0 + bb) * T + (t0 + i)) * NCH + nn] =
            slds[i * 65 + bb * 4 + nn];
      }
    }
    __syncthreads();
  }
}

// ===================== Fallback: round-1 fused kernel ======================
namespace fb {
constexpr int TT = 128, NT = T / TT, XPAD = 76, THREADS = 512;
}
__global__ __launch_bounds__(fb::THREADS, 2)
void lif_fused(const float* __restrict__ x, const float* __restrict__ tda,
               const float* __restrict__ Wsp, const float* __restrict__ lat,
               const float* __restrict__ Wtda, const float* __restrict__ btda,
               float* __restrict__ out)
{
  using namespace fb;
  __shared__ float  xl[2][TT * XPAD];
  __shared__ double wl[NCH * C];
  __shared__ double projl[TT * NCH];
  __shared__ float  spikel[TT * NCH];
  __shared__ double thl[NCH];
  const int b = blockIdx.x, tid = threadIdx.x;
  const int n = tid & 3, tl = tid >> 2;
  if (tid < NCH) {
    double z = (double)btda[tid];
    for (int j = 0; j < TDAF; ++j)
      z += (double)tda[b * TDAF + j] * (double)Wtda[tid * TDAF + j];
    thl[tid] = 1.0 + 0.3 / (1.0 + exp(-z));
  }
  if (tid < NCH * C) {
    const int c = tid >> 2, nn = tid & 3;
    double s = 0.0;
    for (int m = 0; m < NCH; ++m)
      s += (double)Wsp[m * C + c] * (double)lat[m * NCH + nn];
    wl[nn * C + c] = s;
  }
  __syncthreads();
  double w[C];
  #pragma unroll
  for (int j = 0; j < C; ++j) w[j] = wl[n * C + j];
  const double th = thl[n];
  const float4* gx = reinterpret_cast<const float4*>(x) + (size_t)b * (T * C / 4);
  float4 ra[4], rb[4];
  #pragma unroll
  for (int r = 0; r < 4; ++r) ra[r] = gx[tid + THREADS * r];
  double pre = 0.0;
  bool sflag = true;
  auto stage = [&](int buf, const float4* rr) {
    #pragma unroll
    for (int r = 0; r < 4; ++r) {
      const int f = tid + THREADS * r;
      const int t = f >> 4, c4 = (f & 15) << 2;
      *reinterpret_cast<float4*>(&xl[buf][t * XPAD + c4]) = rr[r];
    }
  };
  auto prefetch = [&](int k, float4* rr) {
    const float4* src = gx + (size_t)k * (TT * C / 4);
    #pragma unroll
    for (int r = 0; r < 4; ++r) rr[r] = src[tid + THREADS * r];
  };
  auto tilework = [&](int buf, int k) {
    __syncthreads();
    const float* row = &xl[buf][tl * XPAD];
    double a0 = 0.0, a1 = 0.0;
    #pragma unroll
    for (int q = 0; q < 16; ++q) {
      const float4 v = *reinterpret_cast<const float4*>(&row[4 * q]);
      a0 = fma((double)v.x, w[4 * q + 0], a0);
      a1 = fma((double)v.y, w[4 * q + 1], a1);
      a0 = fma((double)v.z, w[4 * q + 2], a0);
      a1 = fma((double)v.w, w[4 * q + 3], a1);
    }
    projl[tid] = a0 + a1;
    __syncthreads();
    if (tid < NCH) {
      #pragma unroll 4
      for (int t = 0; t < TT; ++t) {
        const double p  = projl[t * NCH + tid];
        const double ac = fma(LEAK, pre, p);
        pre   = sflag ? p : ac;
        sflag = (pre >= th);
        spikel[t * NCH + tid] = sflag ? 1.0f : 0.0f;
      }
    }
    __syncthreads();
    out[((size_t)b * T + (size_t)k * TT) * NCH + tid] = spikel[tid];
  };
  for (int k = 0; k < NT; k += 2) {
    stage(0, ra);
    if (k + 1 < NT) prefetch(k + 1, rb);
    tilework(0, k);
    stage(1, rb);
    if (k + 2 < NT) prefetch(k + 2, ra);
    tilework(1, k + 1);
  }
}

extern "C" void kernel_launch(void* const* d_in, const int* in_sizes, int n_in,
                              void* d_out, int out_size, void* d_ws, size_t ws_size,
                              hipStream_t stream) {
  const float* x    = (const float*)d_in[0];
  const float* tda  = (const float*)d_in[1];
  const float* Wsp  = (const float*)d_in[2];
  const float* lat  = (const float*)d_in[3];
  const float* Wtda = (const float*)d_in[4];
  const float* btda = (const float*)d_in[5];
  float* out = (float*)d_out;
  const int B = in_sizes[0] / (T * C);

  const size_t need = (size_t)T * (size_t)B * NCH * sizeof(double);
  if (ws_size >= need && (B % 4) == 0) {
    double* proj = (double*)d_ws;
    const int grid1 = (B / 4) * (T / 64);
    lif_proj<<<grid1, 128, 0, stream>>>(x, Wsp, lat, proj, B);
    const int grid2 = (B * NCH) / 64;
    lif_scan<<<grid2, 64, 0, stream>>>(proj, tda, Wtda, btda, out, B);
  } else {
    lif_fused<<<B, fb::THREADS, 0, stream>>>(x, tda, Wsp, lat, Wtda, btda, out);
  }
}